// Round 1
// baseline (119.146 us; speedup 1.0000x reference)
//
#include <hip/hip_runtime.h>

#define BB   8
#define NBL  2000
#define KG   5
#define RR   10000
#define XDIM 2000
#define DINW 400

// ---------------- k1: mem2[k][b][nb] = x[b]·W_fc[r] + b_fc[r] + b_fv[r] + 0.05, r = nb*5+k
__global__ __launch_bounds__(256) void k1_gemm(
    const float* __restrict__ in1, const float* __restrict__ in2,
    const float* __restrict__ in3, const float* __restrict__ in4,
    const float* __restrict__ in5,
    const float* __restrict__ Wfc, const float* __restrict__ bfc,
    const float* __restrict__ bfv, float* __restrict__ mem2)
{
    __shared__ float xs[BB][2048];
    const int tid = threadIdx.x;

    // stage x = concat(in1..in5) into LDS, padded to 2048 cols with zeros
    #pragma unroll
    for (int wh = 0; wh < 5; ++wh) {
        const float* p = (wh==0)?in1:(wh==1)?in2:(wh==2)?in3:(wh==3)?in4:in5;
        for (int t = tid; t < BB*DINW; t += 256) {
            int b = t / DINW, d = t - b*DINW;
            xs[b][wh*DINW + d] = p[t];
        }
    }
    for (int t = tid; t < BB*48; t += 256) {
        int b = t / 48, j = XDIM + (t - b*48);
        xs[b][j] = 0.f;
    }
    __syncthreads();

    const int wave = tid >> 6, lane = tid & 63;
    const int rbase = blockIdx.x * 20 + wave * 5;   // 500 blocks * 20 rows = 10000

    float acc[5][BB];
    #pragma unroll
    for (int q = 0; q < 5; ++q)
        #pragma unroll
        for (int b = 0; b < BB; ++b) acc[q][b] = 0.f;

    #pragma unroll
    for (int i = 0; i < 8; ++i) {
        const int col = i*256 + (lane << 2);
        const bool valid = col < XDIM;
        float4 w[5];
        #pragma unroll
        for (int q = 0; q < 5; ++q) {
            w[q] = valid ? *(const float4*)(Wfc + (rbase+q)*XDIM + col)
                         : make_float4(0.f,0.f,0.f,0.f);
        }
        #pragma unroll
        for (int b = 0; b < BB; ++b) {
            float4 xv = *(const float4*)&xs[b][col];   // col <= 2044, pad is zero
            #pragma unroll
            for (int q = 0; q < 5; ++q) {
                acc[q][b] += w[q].x*xv.x + w[q].y*xv.y + w[q].z*xv.z + w[q].w*xv.w;
            }
        }
    }

    // cross-lane reduce and write (compile-time acc indices only)
    #pragma unroll
    for (int q = 0; q < 5; ++q) {
        const int r = rbase + q;
        const int k = r % 5, nb = r / 5;
        #pragma unroll
        for (int b = 0; b < BB; ++b) {
            float v = acc[q][b];
            #pragma unroll
            for (int off = 32; off >= 1; off >>= 1) v += __shfl_xor(v, off, 64);
            if (lane == 0)
                mem2[(k*BB + b)*NBL + nb] = v + bfc[r] + bfv[r] + 0.05f;
        }
    }
}

// ---------------- k2: exact order stats 160/161 per (b,k) via radix select
__device__ __forceinline__ unsigned sortkey(float f) {
    unsigned u = __float_as_uint(f);
    return (u & 0x80000000u) ? ~u : (u | 0x80000000u);
}
__device__ __forceinline__ float unsortkey(unsigned u) {
    unsigned ub = (u & 0x80000000u) ? (u ^ 0x80000000u) : ~u;
    return __uint_as_float(ub);
}

__global__ __launch_bounds__(64) void k2_nps(const float* __restrict__ mem2,
                                             float* __restrict__ nps)
{
    const int idx = blockIdx.x;           // idx = b*5 + k
    const int b = idx / 5, k = idx - b*5;
    const int lane = threadIdx.x;
    const float* src = mem2 + (k*BB + b)*NBL;

    unsigned u[32];
    #pragma unroll
    for (int i = 0; i < 32; ++i) {
        int nb = i*64 + lane;
        u[i] = (nb < NBL) ? sortkey(src[nb]) : 0u;   // pad = smallest key
    }

    // 160th largest (0-indexed 159): max X with count(u >= X) >= 160
    unsigned X = 0;
    for (int bit = 31; bit >= 0; --bit) {
        unsigned cand = X | (1u << bit);
        int c = 0;
        #pragma unroll
        for (int i = 0; i < 32; ++i) c += (u[i] >= cand) ? 1 : 0;
        #pragma unroll
        for (int off = 32; off >= 1; off >>= 1) c += __shfl_xor(c, off, 64);
        if (c >= 160) X = cand;
    }
    const unsigned q2u = X;               // mem_q2 (rank 159)

    int cge = 0;
    #pragma unroll
    for (int i = 0; i < 32; ++i) cge += (u[i] >= q2u) ? 1 : 0;
    #pragma unroll
    for (int off = 32; off >= 1; off >>= 1) cge += __shfl_xor(cge, off, 64);

    unsigned q1u;
    if (cge >= 161) {
        q1u = q2u;                        // ties reach rank 160
    } else {
        unsigned m = 0;
        #pragma unroll
        for (int i = 0; i < 32; ++i) if (u[i] < q2u && u[i] > m) m = u[i];
        #pragma unroll
        for (int off = 32; off >= 1; off >>= 1) {
            unsigned o = __shfl_xor(m, off, 64);
            m = (o > m) ? o : m;
        }
        q1u = m;                          // mem_q1 (rank 160)
    }

    if (lane == 0) {
        float q2 = unsortkey(q2u), q1 = unsortkey(q1u);
        nps[idx] = q1 + (q2 - q1) * 0.2f;
    }
}

// ---------------- k3: spike = (mem - nps > thr), scattered to reference layout
__global__ __launch_bounds__(256) void k3_spike(const float* __restrict__ mem2,
                                                const float* __restrict__ nps,
                                                float* __restrict__ spike_out)
{
    int g = blockIdx.x * 256 + threadIdx.x;
    if (g >= KG*BB*NBL) return;
    int k   = g / (BB*NBL);
    int rem = g - k*(BB*NBL);
    int b   = rem / NBL;
    int nb  = rem - b*NBL;
    float v = mem2[g] - nps[b*5 + k];
    spike_out[b*RR + nb*5 + k] = (v > 0.1f) ? 1.0f : 0.0f;
}

// ---------------- k4: out[b][o] = spike[b]·W_mlp[o] + b_mlp[o]
__global__ __launch_bounds__(256) void k4_out(const float* __restrict__ Wmlp,
                                              const float* __restrict__ bmlp,
                                              const float* __restrict__ spike,
                                              float* __restrict__ out)
{
    const int o = blockIdx.x;
    const int tid = threadIdx.x;
    const int wave = tid >> 6, lane = tid & 63;

    float acc[BB];
    #pragma unroll
    for (int b = 0; b < BB; ++b) acc[b] = 0.f;

    #pragma unroll
    for (int i = 0; i < 10; ++i) {
        int col = i*1024 + tid*4;
        if (col < RR) {
            float4 w = *(const float4*)(Wmlp + o*RR + col);
            #pragma unroll
            for (int b = 0; b < BB; ++b) {
                float4 s = *(const float4*)(spike + b*RR + col);
                acc[b] += w.x*s.x + w.y*s.y + w.z*s.z + w.w*s.w;
            }
        }
    }

    __shared__ float red[4][BB];
    #pragma unroll
    for (int b = 0; b < BB; ++b) {
        float v = acc[b];
        #pragma unroll
        for (int off = 32; off >= 1; off >>= 1) v += __shfl_xor(v, off, 64);
        if (lane == 0) red[wave][b] = v;
    }
    __syncthreads();
    if (tid < BB) {
        float v = red[0][tid] + red[1][tid] + red[2][tid] + red[3][tid];
        out[tid*100 + o] = v + bmlp[o];
    }
}

extern "C" void kernel_launch(void* const* d_in, const int* in_sizes, int n_in,
                              void* d_out, int out_size, void* d_ws, size_t ws_size,
                              hipStream_t stream) {
    const float* in1  = (const float*)d_in[0];
    const float* in2  = (const float*)d_in[1];
    const float* in3  = (const float*)d_in[2];
    const float* in4  = (const float*)d_in[3];
    const float* in5  = (const float*)d_in[4];
    const float* Wfc  = (const float*)d_in[5];
    const float* bfc  = (const float*)d_in[6];
    // d_in[7] = W_fv : multiplied by zero spikes — never read (saves 400 MB)
    const float* bfv  = (const float*)d_in[8];
    const float* Wmlp = (const float*)d_in[9];
    const float* bmlp = (const float*)d_in[10];

    float* out   = (float*)d_out;        // 8*100 = 800 floats
    float* spike = out + 800;            // 8*10000 = 80000 floats (r_sumspike)

    float* mem2 = (float*)d_ws;          // 80000 floats, layout [k][b][nb]
    float* nps  = mem2 + 80000;          // 40 floats

    k1_gemm<<<500, 256, 0, stream>>>(in1, in2, in3, in4, in5, Wfc, bfc, bfv, mem2);
    k2_nps<<<40, 64, 0, stream>>>(mem2, nps);
    k3_spike<<<(KG*BB*NBL + 255)/256, 256, 0, stream>>>(mem2, nps, spike);
    k4_out<<<100, 256, 0, stream>>>(Wmlp, bmlp, spike, out);
}

// Round 2
// 86.852 us; speedup vs baseline: 1.3718x; 1.3718x over previous
//
#include <hip/hip_runtime.h>

#define BB   8
#define NBL  2000
#define KG   5
#define RR   10000
#define XDIM 2000

// ---------------- k1: mem2[k][b][nb] = x[b]·W_fc[r] + b_fc[r] + b_fv[r] + 0.05, r = nb*5+k
// 500 blocks × 256 threads; wave w of block bl owns rows r = (bl*4+w)*5 .. +4
__global__ __launch_bounds__(256) void k1_gemm(
    const float* __restrict__ in1, const float* __restrict__ in2,
    const float* __restrict__ in3, const float* __restrict__ in4,
    const float* __restrict__ in5,
    const float* __restrict__ Wfc, const float* __restrict__ bfc,
    const float* __restrict__ bfv, float* __restrict__ mem2)
{
    __shared__ float xs[BB][2048];
    const int tid = threadIdx.x;

    // ---- stage x = concat(in1..in5) into LDS, float4-vectorized (800 f4 per input)
    {
        const float* ins[5] = {in1, in2, in3, in4, in5};
        #pragma unroll
        for (int wh = 0; wh < 5; ++wh) {
            const float4* p = (const float4*)ins[wh];
            for (int t = tid; t < 800; t += 256) {
                int b = t / 100, d4 = t - b * 100;          // magic-mul div, 3.1 iters/thread
                *(float4*)&xs[b][wh * 400 + d4 * 4] = p[t];
            }
        }
        for (int t = tid; t < 96; t += 256) {               // zero-pad cols 2000..2047
            int b = t / 12, j = t - b * 12;
            *(float4*)&xs[b][2000 + j * 4] = make_float4(0.f, 0.f, 0.f, 0.f);
        }
    }
    __syncthreads();

    const int wave = tid >> 6, lane = tid & 63;
    const int nb = blockIdx.x * 4 + wave;                   // block-neuron index
    const int rbase = nb * 5;

    float acc[5][BB];
    #pragma unroll
    for (int q = 0; q < 5; ++q)
        #pragma unroll
        for (int b = 0; b < BB; ++b) acc[q][b] = 0.f;

    #pragma unroll
    for (int i = 0; i < 8; ++i) {
        const int col = i * 256 + (lane << 2);
        const bool valid = col < XDIM;                      // guard W loads (xs pad is zero)
        float4 w[5];
        #pragma unroll
        for (int q = 0; q < 5; ++q)
            w[q] = valid ? *(const float4*)(Wfc + (size_t)(rbase + q) * XDIM + col)
                         : make_float4(0.f, 0.f, 0.f, 0.f);
        #pragma unroll
        for (int b = 0; b < BB; ++b) {
            float4 xv = *(const float4*)&xs[b][col];
            #pragma unroll
            for (int q = 0; q < 5; ++q)
                acc[q][b] += w[q].x * xv.x + w[q].y * xv.y + w[q].z * xv.z + w[q].w * xv.w;
        }
    }

    // cross-lane reduce (40 independent 6-level chains — ILP hides swizzle latency)
    #pragma unroll
    for (int q = 0; q < 5; ++q) {
        const int r = rbase + q;
        #pragma unroll
        for (int b = 0; b < BB; ++b) {
            float v = acc[q][b];
            #pragma unroll
            for (int off = 32; off >= 1; off >>= 1) v += __shfl_xor(v, off, 64);
            if (lane == 0)
                mem2[(q * BB + b) * NBL + nb] = v + bfc[r] + bfv[r] + 0.05f;
        }
    }
}

// ---------------- k2: exact order stats 160/161 per (b,k) via ballot radix select,
//                      spike write fused (k3 eliminated)
__device__ __forceinline__ unsigned sortkey(float f) {
    unsigned u = __float_as_uint(f);
    return (u & 0x80000000u) ? ~u : (u | 0x80000000u);
}
__device__ __forceinline__ float unsortkey(unsigned u) {
    unsigned ub = (u & 0x80000000u) ? (u ^ 0x80000000u) : ~u;
    return __uint_as_float(ub);
}

__global__ __launch_bounds__(64) void k2_nps_spike(const float* __restrict__ mem2,
                                                   float* __restrict__ spike_out)
{
    const int idx = blockIdx.x;                 // idx = b*5 + k
    const int b = idx / 5, k = idx - b * 5;
    const int lane = threadIdx.x;
    const float* src = mem2 + (k * BB + b) * NBL;

    float    f[32];
    unsigned u[32];
    #pragma unroll
    for (int i = 0; i < 32; ++i) {
        int nb = i * 64 + lane;
        f[i] = (nb < NBL) ? src[nb] : 0.f;
        u[i] = (nb < NBL) ? sortkey(f[i]) : 0u;  // pad key = smallest
    }

    // rank-159 (160th largest): max X with count(u >= X) >= 160.
    // count via ballot+popc: wave-uniform in SGPRs, NO shuffle chains.
    unsigned X = 0;
    for (int bit = 31; bit >= 0; --bit) {
        unsigned cand = X | (1u << bit);
        int c = 0;
        #pragma unroll
        for (int i = 0; i < 32; ++i)
            c += (int)__popcll(__ballot(u[i] >= cand));
        if (c >= 160) X = cand;
    }
    const unsigned q2u = X;                      // mem_q2 (rank 159)

    int cge = 0;
    #pragma unroll
    for (int i = 0; i < 32; ++i)
        cge += (int)__popcll(__ballot(u[i] >= q2u));

    unsigned q1u;
    if (cge >= 161) {
        q1u = q2u;                               // ties reach rank 160
    } else {
        unsigned m = 0;
        #pragma unroll
        for (int i = 0; i < 32; ++i)
            if (u[i] < q2u && u[i] > m) m = u[i];
        #pragma unroll
        for (int off = 32; off >= 1; off >>= 1) {
            unsigned o = __shfl_xor(m, off, 64);
            m = (o > m) ? o : m;
        }
        q1u = m;                                 // mem_q1 (rank 160)
    }

    const float q2 = unsortkey(q2u), q1 = unsortkey(q1u);
    const float nps = q1 + (q2 - q1) * 0.2f;     // uniform across the wave

    // fused spike write: spike = (mem - nps > 0.1)
    #pragma unroll
    for (int i = 0; i < 32; ++i) {
        int nb = i * 64 + lane;
        if (nb < NBL)
            spike_out[b * RR + nb * 5 + k] = (f[i] - nps > 0.1f) ? 1.0f : 0.0f;
    }
}

// ---------------- k4: out[b][o] = spike[b]·W_mlp[o] + b_mlp[o]; 100 blocks × 512
__global__ __launch_bounds__(512) void k4_out(const float* __restrict__ Wmlp,
                                              const float* __restrict__ bmlp,
                                              const float* __restrict__ spike,
                                              float* __restrict__ out)
{
    const int o = blockIdx.x;
    const int tid = threadIdx.x;
    const int wave = tid >> 6, lane = tid & 63;

    float acc[BB];
    #pragma unroll
    for (int b = 0; b < BB; ++b) acc[b] = 0.f;

    #pragma unroll
    for (int i = 0; i < 5; ++i) {
        int col = i * 2048 + tid * 4;            // 512 thr × f4 = 2048 floats/iter
        if (col < RR) {                          // last valid f4 at col 9996
            float4 w = *(const float4*)(Wmlp + (size_t)o * RR + col);
            #pragma unroll
            for (int b = 0; b < BB; ++b) {
                float4 s = *(const float4*)(spike + b * RR + col);
                acc[b] += w.x * s.x + w.y * s.y + w.z * s.z + w.w * s.w;
            }
        }
    }

    __shared__ float red[8][BB];
    #pragma unroll
    for (int b = 0; b < BB; ++b) {
        float v = acc[b];
        #pragma unroll
        for (int off = 32; off >= 1; off >>= 1) v += __shfl_xor(v, off, 64);
        if (lane == 0) red[wave][b] = v;
    }
    __syncthreads();
    if (tid < BB) {
        float v = 0.f;
        #pragma unroll
        for (int w = 0; w < 8; ++w) v += red[w][tid];
        out[tid * 100 + o] = v + bmlp[o];
    }
}

extern "C" void kernel_launch(void* const* d_in, const int* in_sizes, int n_in,
                              void* d_out, int out_size, void* d_ws, size_t ws_size,
                              hipStream_t stream) {
    const float* in1  = (const float*)d_in[0];
    const float* in2  = (const float*)d_in[1];
    const float* in3  = (const float*)d_in[2];
    const float* in4  = (const float*)d_in[3];
    const float* in5  = (const float*)d_in[4];
    const float* Wfc  = (const float*)d_in[5];
    const float* bfc  = (const float*)d_in[6];
    // d_in[7] = W_fv : multiplied by zero spikes — never read (saves 400 MB)
    const float* bfv  = (const float*)d_in[8];
    const float* Wmlp = (const float*)d_in[9];
    const float* bmlp = (const float*)d_in[10];

    float* out   = (float*)d_out;        // 8*100 = 800 floats
    float* spike = out + 800;            // 8*10000 floats (r_sumspike)

    float* mem2 = (float*)d_ws;          // 80000 floats, layout [k][b][nb]

    k1_gemm<<<500, 256, 0, stream>>>(in1, in2, in3, in4, in5, Wfc, bfc, bfv, mem2);
    k2_nps_spike<<<40, 64, 0, stream>>>(mem2, spike);
    k4_out<<<100, 512, 0, stream>>>(Wmlp, bmlp, spike, out);
}

// Round 3
// 81.208 us; speedup vs baseline: 1.4672x; 1.0695x over previous
//
#include <hip/hip_runtime.h>

#define BB   8
#define NBL  2000
#define KG   5
#define RR   10000
#define XDIM 2000

// ---------------- kernel A: mem2[k][b][nb] = x[b]·W_fc[r] + b_fc[r] + b_fv[r] + 0.05
// r = nb*5+k. 500 blocks × 256 thr, one nb per wave, NO LDS (x served from L1/L2).
__global__ __launch_bounds__(256) void kA_gemm(
    const float* __restrict__ in1, const float* __restrict__ in2,
    const float* __restrict__ in3, const float* __restrict__ in4,
    const float* __restrict__ in5,
    const float* __restrict__ Wfc, const float* __restrict__ bfc,
    const float* __restrict__ bfv, float* __restrict__ mem2,
    unsigned* __restrict__ counter)
{
    // re-arm the kernel-B barrier every call (stream order makes it visible to kB)
    if (blockIdx.x == 0 && threadIdx.x == 0) *counter = 0u;

    const int tid  = threadIdx.x;
    const int wave = tid >> 6, lane = tid & 63;
    const int nb    = blockIdx.x * 4 + wave;        // 0..1999
    const int rbase = nb * 5;

    float acc[5][BB];
    #pragma unroll
    for (int q = 0; q < 5; ++q)
        #pragma unroll
        for (int b = 0; b < BB; ++b) acc[q][b] = 0.f;

    #pragma unroll
    for (int i = 0; i < 8; ++i) {
        const int col = i * 256 + (lane << 2);      // 0..2044, float4-aligned
        const bool valid = col < XDIM;              // i==7 tail: lanes >=52 idle
        // per-lane x source: concat segment wh = col/400, offset within input
        const int wh  = col / 400;                  // 0..5 (5 only when invalid)
        const int off = col - wh * 400;             // float4 never crosses a 400-boundary
        const float* xp = in1;
        xp = (wh == 1) ? in2 : xp;
        xp = (wh == 2) ? in3 : xp;
        xp = (wh == 3) ? in4 : xp;
        xp = (wh == 4) ? in5 : xp;

        float4 w[5];
        #pragma unroll
        for (int q = 0; q < 5; ++q)
            w[q] = valid ? *(const float4*)(Wfc + (size_t)(rbase + q) * XDIM + col)
                         : make_float4(0.f, 0.f, 0.f, 0.f);

        #pragma unroll
        for (int b = 0; b < BB; ++b) {
            float4 xv = valid ? *(const float4*)(xp + b * 400 + off)
                              : make_float4(0.f, 0.f, 0.f, 0.f);
            #pragma unroll
            for (int q = 0; q < 5; ++q)
                acc[q][b] += w[q].x * xv.x + w[q].y * xv.y + w[q].z * xv.z + w[q].w * xv.w;
        }
    }

    // cross-lane reduce (40 independent chains — ILP hides swizzle latency)
    #pragma unroll
    for (int q = 0; q < 5; ++q) {
        const int r = rbase + q;
        #pragma unroll
        for (int b = 0; b < BB; ++b) {
            float v = acc[q][b];
            #pragma unroll
            for (int o = 32; o >= 1; o >>= 1) v += __shfl_xor(v, o, 64);
            if (lane == 0)
                mem2[(q * BB + b) * NBL + nb] = v + bfc[r] + bfv[r] + 0.05f;
        }
    }
}

// ---------------- kernel B: fused {radix-select nps + spike} -> barrier -> MLP GEMV
__device__ __forceinline__ unsigned sortkey(float f) {
    unsigned u = __float_as_uint(f);
    return (u & 0x80000000u) ? ~u : (u | 0x80000000u);
}
__device__ __forceinline__ float unsortkey(unsigned u) {
    unsigned ub = (u & 0x80000000u) ? (u ^ 0x80000000u) : ~u;
    return __uint_as_float(ub);
}

__global__ __launch_bounds__(512) void kB_spike_out(
    const float* __restrict__ mem2, const float* __restrict__ Wmlp,
    const float* __restrict__ bmlp, float* __restrict__ spike_out,
    float* __restrict__ out, unsigned* __restrict__ counter)
{
    const int tid = threadIdx.x;
    const int blk = blockIdx.x;                      // 100 blocks

    // ---- phase A: blocks 0..39, wave 0 only — exact order stats + spike write
    if (blk < 40 && tid < 64) {
        const int b = blk / 5, k = blk - b * 5;
        const int lane = tid;
        const float* src = mem2 + (k * BB + b) * NBL;

        float    f[32];
        unsigned u[32];
        #pragma unroll
        for (int i = 0; i < 32; ++i) {
            int nb = i * 64 + lane;
            f[i] = (nb < NBL) ? src[nb] : 0.f;
            u[i] = (nb < NBL) ? sortkey(f[i]) : 0u;  // pad key = smallest
        }

        // rank-159 (160th largest): max X with count(u >= X) >= 160 (ballot+popc)
        unsigned X = 0;
        for (int bit = 31; bit >= 0; --bit) {
            unsigned cand = X | (1u << bit);
            int c = 0;
            #pragma unroll
            for (int i = 0; i < 32; ++i)
                c += (int)__popcll(__ballot(u[i] >= cand));
            if (c >= 160) X = cand;
        }
        const unsigned q2u = X;                      // mem_q2 (rank 159)

        int cge = 0;
        #pragma unroll
        for (int i = 0; i < 32; ++i)
            cge += (int)__popcll(__ballot(u[i] >= q2u));

        unsigned q1u;
        if (cge >= 161) {
            q1u = q2u;                               // ties reach rank 160
        } else {
            unsigned m = 0;
            #pragma unroll
            for (int i = 0; i < 32; ++i)
                if (u[i] < q2u && u[i] > m) m = u[i];
            #pragma unroll
            for (int o = 32; o >= 1; o >>= 1) {
                unsigned ot = __shfl_xor(m, o, 64);
                m = (ot > m) ? ot : m;
            }
            q1u = m;                                 // mem_q1 (rank 160)
        }

        const float q2 = unsortkey(q2u), q1 = unsortkey(q1u);
        const float nps = q1 + (q2 - q1) * 0.2f;

        #pragma unroll
        for (int i = 0; i < 32; ++i) {
            int nb = i * 64 + lane;
            if (nb < NBL)
                spike_out[b * RR + nb * 5 + k] = (f[i] - nps > 0.1f) ? 1.0f : 0.0f;
        }
        __threadfence();                             // agent-scope release of spike stores
        if (lane == 0) atomicAdd(counter, 1u);       // device-scope by default
    }

    // ---- barrier: all 100 blocks co-resident (<=256 CUs), spin on counter
    __syncthreads();
    if (tid == 0) {
        while (__hip_atomic_load(counter, __ATOMIC_ACQUIRE, __HIP_MEMORY_SCOPE_AGENT) < 40u)
            __builtin_amdgcn_s_sleep(2);
        __threadfence();                             // belt-and-braces acquire
    }
    __syncthreads();

    // ---- phase B: block = output column o; out[b][o] = spike[b]·W_mlp[o] + b_mlp[o]
    const int o = blk;
    const int wave = tid >> 6, lane = tid & 63;

    float acc[BB];
    #pragma unroll
    for (int b = 0; b < BB; ++b) acc[b] = 0.f;

    #pragma unroll
    for (int i = 0; i < 5; ++i) {
        int col = i * 2048 + tid * 4;                // 512 thr × f4 = 2048 floats/iter
        if (col < RR) {                              // last valid f4 at 9996
            float4 w = *(const float4*)(Wmlp + (size_t)o * RR + col);
            #pragma unroll
            for (int b = 0; b < BB; ++b) {
                float4 s = *(const float4*)(spike_out + b * RR + col);
                acc[b] += w.x * s.x + w.y * s.y + w.z * s.z + w.w * s.w;
            }
        }
    }

    __shared__ float red[8][BB];
    #pragma unroll
    for (int b = 0; b < BB; ++b) {
        float v = acc[b];
        #pragma unroll
        for (int off = 32; off >= 1; off >>= 1) v += __shfl_xor(v, off, 64);
        if (lane == 0) red[wave][b] = v;
    }
    __syncthreads();
    if (tid < BB) {
        float v = 0.f;
        #pragma unroll
        for (int w = 0; w < 8; ++w) v += red[w][tid];
        out[tid * 100 + o] = v + bmlp[o];
    }
}

extern "C" void kernel_launch(void* const* d_in, const int* in_sizes, int n_in,
                              void* d_out, int out_size, void* d_ws, size_t ws_size,
                              hipStream_t stream) {
    const float* in1  = (const float*)d_in[0];
    const float* in2  = (const float*)d_in[1];
    const float* in3  = (const float*)d_in[2];
    const float* in4  = (const float*)d_in[3];
    const float* in5  = (const float*)d_in[4];
    const float* Wfc  = (const float*)d_in[5];
    const float* bfc  = (const float*)d_in[6];
    // d_in[7] = W_fv : multiplied by zero spikes — never read (saves 400 MB)
    const float* bfv  = (const float*)d_in[8];
    const float* Wmlp = (const float*)d_in[9];
    const float* bmlp = (const float*)d_in[10];

    float* out   = (float*)d_out;          // 8*100 = 800 floats
    float* spike = out + 800;              // 8*10000 floats (r_sumspike)

    float*    mem2    = (float*)d_ws;      // 80000 floats, layout [k][b][nb]
    unsigned* counter = (unsigned*)((char*)d_ws + 80000 * sizeof(float));

    kA_gemm<<<500, 256, 0, stream>>>(in1, in2, in3, in4, in5, Wfc, bfc, bfv,
                                     mem2, counter);
    kB_spike_out<<<100, 512, 0, stream>>>(mem2, Wmlp, bmlp, spike, out, counter);
}